// Round 15
// baseline (238.802 us; speedup 1.0000x reference)
//
#include <hip/hip_runtime.h>
#include <hip/hip_bf16.h>

// WindowAttention fused kernel v18 (MI355X / gfx950)
// One block = one window. 4 waves, wave = head everywhere.
// v18 = v11 (champion, 236us) + K=16 MFMA direct-operand restructure:
//  - QK^T and PV use v_mfma_f32_16x16x16_bf16 (A/B = 4 bf16/lane, k=g*4+e),
//    whose fragment layouts MATCH our packed D-outputs exactly:
//      pkK[vi][mt] == A-frag (m=key tok, k=chan)  -> kb shuffles (32) deleted
//      pkn[mt]     == B-frag (k=key, n=q)         -> pkn shuffles (64) deleted
//      pkV[dt][mt] == A-frag (m=d, k=key)         -> va shuffles (32) deleted
//    128 ds_bpermute/wave removed from the hottest pipe (LDS ~50% busy incl
//    2.15e7 conflict cy) and from the nt-loop serial chains. +32 MFMA (half-
//    FLOP K=16) on a 14%-busy pipe.
//  - qb16: 8x b64 Q-LDS reads (same bytes/regs as v11's 4x b128).
//  - C/D layouts identical -> softmax path + O-store byte-identical to v11.
//  - register-neutral: post-prologue live = pkK+pkV+qb16 = 48 = v11's
//    kb+qb+va. Phase 0/1/4 byte-identical to v11.

#define T49  49
#define CDIM 128
#define NW   64
#define SCALEF 0.17677669529663689f   // 1/sqrt(32)

typedef short bf16x8 __attribute__((ext_vector_type(8)));
typedef short bf16x4 __attribute__((ext_vector_type(4)));
typedef float f32x4  __attribute__((ext_vector_type(4)));

union B8 { unsigned int u[4]; bf16x8 v; };
union B4 { unsigned int u[2]; bf16x4 v; };

__device__ __forceinline__ unsigned int pk2(float a, float b) {
  __hip_bfloat162 h = __float22bfloat162_rn(make_float2(a, b));
  unsigned int u;
  __builtin_memcpy(&u, &h, 4);
  return u;
}

__device__ __forceinline__ unsigned short f2bf(float f) {
  unsigned int u = __builtin_bit_cast(unsigned int, f);
  u += 0x7fffu + ((u >> 16) & 1u);
  return (unsigned short)(u >> 16);
}

// prep: bf16 weights (Q rows pre-scaled by SCALEF) + padded mask
//   maskp[w][q][k] = mask - rowmax(mask)  (q<49,k<49)
//                  = -1e30                (q<49,k>=49)  -> exp()=0 exactly
//                  = 0                    (q>=49)       -> finite garbage, unused
__global__ void prep_kernel(const float* __restrict__ wq, const float* __restrict__ wp,
                            const float* __restrict__ mask,
                            short* __restrict__ wq_bf, short* __restrict__ wp_bf,
                            float* __restrict__ maskp) {
  const int i = blockIdx.x * 256 + threadIdx.x;      // grid covers 262144
  const int w = i >> 12, q = (i >> 6) & 63, k = i & 63;
  // one wave == one (w,q) row, lane == k  (256 % 64 == 0)
  float val = -3.0e38f;
  if (q < T49 && k < T49) val = mask[(w * T49 + q) * T49 + k];
  float rm = val;
  rm = fmaxf(rm, __shfl_xor(rm, 1, 64));
  rm = fmaxf(rm, __shfl_xor(rm, 2, 64));
  rm = fmaxf(rm, __shfl_xor(rm, 4, 64));
  rm = fmaxf(rm, __shfl_xor(rm, 8, 64));
  rm = fmaxf(rm, __shfl_xor(rm, 16, 64));
  rm = fmaxf(rm, __shfl_xor(rm, 32, 64));
  float mv;
  if (q >= T49)      mv = 0.0f;
  else if (k >= T49) mv = -1e30f;
  else               mv = val - rm;
  maskp[i] = mv;
  if (i < 3 * CDIM * CDIM) {
    float wv_ = wq[i];
    if (i < CDIM * CDIM) wv_ *= SCALEF;              // Q rows pre-scaled
    wq_bf[i] = (short)f2bf(wv_);
  }
  if (i < CDIM * CDIM) wp_bf[i] = (short)f2bf(wp[i]);
}

__global__ __launch_bounds__(256, 4)
void winattn_kernel(const float* __restrict__ x, const float* __restrict__ maskp,
                    const float* __restrict__ b_qkv, const float* __restrict__ b_proj,
                    const short* __restrict__ wq, const short* __restrict__ wp,
                    float* __restrict__ out) {
  // LDS (32 KB):
  //  X [64 t][128 ch] bf16 @0,     swz: cbyte ^ ((t&7)<<4); dead after ph1 reads
  //  O [64 t][128 ch] bf16 @0 aliases X, swz: chbyte ^ ((t&7)<<5)
  //  Q [4h][64 t][32 d] bf16 @16384, swz: dbyte ^ ((t&3)<<4)
  //  K,V: registers only (pkK, pkV) -- consumed DIRECTLY by K=16 MFMAs
  __shared__ __align__(16) char smem[32768];
  constexpr int XO_BASE = 0, Q_BASE = 16384;

  const int bw    = blockIdx.x;
  const int wv    = threadIdx.x >> 6;
  const int lane  = threadIdx.x & 63;
  const int g     = lane >> 4;
  const int j16   = lane & 15;
  const int wmask = bw & (NW - 1);

  // ---------------- Phase 0: stage x -> LDS bf16, swizzled (ONCE per block) ----------------
  {
    const int tid = threadIdx.x;
    const int t   = tid >> 2;            // 0..63
    const int c0  = (tid & 3) * 32;      // 32 consecutive channels per thread
    char* wb = smem + XO_BASE + t * 256;
    const int swz = (t & 7) << 4;
    if (t < T49) {
      const float* p = x + (size_t)bw * (T49 * CDIM) + t * CDIM + c0;
#pragma unroll
      for (int q = 0; q < 4; ++q) {
        const float4 v0 = *(const float4*)(p + q * 8);
        const float4 v1 = *(const float4*)(p + q * 8 + 4);
        uint4 u;
        u.x = pk2(v0.x, v0.y); u.y = pk2(v0.z, v0.w);
        u.z = pk2(v1.x, v1.y); u.w = pk2(v1.z, v1.w);
        *(uint4*)(wb + ((c0 * 2 + q * 16) ^ swz)) = u;
      }
    } else {
#pragma unroll
      for (int q = 0; q < 4; ++q)
        *(uint4*)(wb + ((c0 * 2 + q * 16) ^ swz)) = make_uint4(0u, 0u, 0u, 0u);
    }
  }
  __syncthreads();

  // x fragment from LDS: serves as A (natural, m=t) AND B (swapped, n=t)
  auto XF = [&](int tt, int kt) -> bf16x8 {
    const int t = tt * 16 + j16;
    return *(const bf16x8*)(smem + XO_BASE + t * 256 +
                            ((kt * 64 + g * 16) ^ ((t & 7) << 4)));
  };

  // ---------------- Phase 1: QKV (wave wv = head wv; identical to v11) ----------------
  unsigned int pkK[2][4][2];  // [chan-tile vi][key-tok tile tt][pair]: pairs along channel
  unsigned int pkV[2][4][2];  // [chan-tile vi][tok tile tt][pair]: pairs along token

#pragma unroll
  for (int ni = 0; ni < 6; ++ni) {
    const int ct = (ni < 2) ? (wv * 2 + ni)
                 : (ni < 4) ? (8 + wv * 2 + (ni - 2))
                            : (16 + wv * 2 + (ni - 4));
    bf16x8 wf[4];                                     // w frag: row c=ct*16+j16, k=kt*32+g*8..+7
#pragma unroll
    for (int kt = 0; kt < 4; ++kt)
      wf[kt] = *(const bf16x8*)(wq + (ct * 16 + j16) * CDIM + kt * 32 + g * 8);

    if (ni < 4) {
      // swapped: D[c][t]; lane holds channels c0..c0+3 at token t
      const int   c0 = ct * 16 + g * 4;
      float4 b4 = *(const float4*)(b_qkv + c0);
      if (ni < 2) { b4.x *= SCALEF; b4.y *= SCALEF; b4.z *= SCALEF; b4.w *= SCALEF; }
      const f32x4 cin = {b4.x, b4.y, b4.z, b4.w};    // bias as C-operand
      if (ni < 2) {
        // Q -> LDS (read back by same wave in prologue)
        char* base = smem + Q_BASE + wv * 4096;
        const int d0 = c0 & 31;
#pragma unroll
        for (int tt = 0; tt < 4; ++tt) {
          f32x4 acc = cin;
#pragma unroll
          for (int kt = 0; kt < 4; ++kt)
            acc = __builtin_amdgcn_mfma_f32_16x16x32_bf16(wf[kt], XF(tt, kt), acc, 0, 0, 0);
          const int t = tt * 16 + j16;
          const uint2 w2 = make_uint2(pk2(acc[0], acc[1]), pk2(acc[2], acc[3]));
          *(uint2*)(base + t * 64 + ((d0 * 2) ^ ((t & 3) << 4))) = w2;
        }
      } else {
        // K -> registers
        const int vi = ni - 2;
#pragma unroll
        for (int tt = 0; tt < 4; ++tt) {
          f32x4 acc = cin;
#pragma unroll
          for (int kt = 0; kt < 4; ++kt)
            acc = __builtin_amdgcn_mfma_f32_16x16x32_bf16(wf[kt], XF(tt, kt), acc, 0, 0, 0);
          pkK[vi][tt][0] = pk2(acc[0], acc[1]);
          pkK[vi][tt][1] = pk2(acc[2], acc[3]);
        }
      }
    } else {
      // V natural: D[t][c]; bias constant across rows -> C-operand splat
      const int   vi   = ni - 4;
      const float bias = b_qkv[ct * 16 + j16];
      const f32x4 cin = {bias, bias, bias, bias};
#pragma unroll
      for (int tt = 0; tt < 4; ++tt) {
        f32x4 acc = cin;
#pragma unroll
        for (int kt = 0; kt < 4; ++kt)
          acc = __builtin_amdgcn_mfma_f32_16x16x32_bf16(XF(tt, kt), wf[kt], acc, 0, 0, 0);
        pkV[vi][tt][0] = pk2(acc[0], acc[1]);
        pkV[vi][tt][1] = pk2(acc[2], acc[3]);
      }
    }
  }
  // NO barrier: qb16 reads this wave's own Q writes; pkK/pkV already in regs.

  // ---------------- Prologue: qb16 from own Q LDS (B-frags for K=16 MFMA) ----------------
  // qb16[vi][nt]: B[k = chan vi*16+g*4+e][n = q = nt*16+j16], 4 bf16 = b64 read.
  const char* Qb = smem + Q_BASE + wv * 4096;
  B4 qb16[2][4];
#pragma unroll
  for (int nt = 0; nt < 4; ++nt) {
    const int q = nt * 16 + j16;
#pragma unroll
    for (int vi = 0; vi < 2; ++vi) {
      const uint2 r = *(const uint2*)(Qb + q * 64 + ((vi * 32 + g * 8) ^ ((q & 3) << 4)));
      qb16[vi][nt].u[0] = r.x;
      qb16[vi][nt].u[1] = r.y;
    }
  }

  __syncthreads();   // all X reads (ph1) + own Q reads done -> O may overwrite X

  // ---------------- Phases 2+3 merged, per q-tile nt (wave = head) ----------------
  char*        Ob  = smem + XO_BASE;
  const float* mwb = maskp + wmask * 4096;

#pragma unroll
  for (int nt = 0; nt < 4; ++nt) {
    const float* mp = mwb + (nt * 16 + j16) * 64 + g * 4;
    float v[4][4];
#pragma unroll
    for (int mt = 0; mt < 4; ++mt) {
      const float4 m4 = *(const float4*)(mp + mt * 16);
      const f32x4 cin = {m4.x, m4.y, m4.z, m4.w};    // mask as C-operand
      // S^T[key][q] via two chained K=16 MFMAs (chan 0-15, then 16-31):
      // A = pkK[vi][mt] (m=key tok, k=chan), B = qb16[vi][nt] (k=chan, n=q)
      B4 ka0, ka1;
      ka0.u[0] = pkK[0][mt][0]; ka0.u[1] = pkK[0][mt][1];
      ka1.u[0] = pkK[1][mt][0]; ka1.u[1] = pkK[1][mt][1];
      f32x4 s = __builtin_amdgcn_mfma_f32_16x16x16bf16_1k(ka0.v, qb16[0][nt].v, cin, 0, 0, 0);
      s = __builtin_amdgcn_mfma_f32_16x16x16bf16_1k(ka1.v, qb16[1][nt].v, s, 0, 0, 0);
      // mask pre-shifted by row max in prep: exp directly, no max pass
      v[mt][0] = __expf(s[0]); v[mt][1] = __expf(s[1]);
      v[mt][2] = __expf(s[2]); v[mt][3] = __expf(s[3]);
    }
    // denominator chain (overlaps PV below)
    float sr[8];
#pragma unroll
    for (int mt = 0; mt < 4; ++mt) {
      sr[2 * mt]     = v[mt][0] + v[mt][1];
      sr[2 * mt + 1] = v[mt][2] + v[mt][3];
    }
    float sum = ((sr[0] + sr[1]) + (sr[2] + sr[3])) + ((sr[4] + sr[5]) + (sr[6] + sr[7]));
    sum += __shfl_xor(sum, 16, 64);
    sum += __shfl_xor(sum, 32, 64);
    const float inv = 1.0f / sum;

    // P^T raw (unnormalized): pairs along key = EXACTLY the K=16 B-frag
    // (k = key mt*16+g*4+e, n = q = j16). No redistribution.
    f32x4 oacc[2] = {{0.f,0.f,0.f,0.f},{0.f,0.f,0.f,0.f}};
#pragma unroll
    for (int mt = 0; mt < 4; ++mt) {
      B4 pb;
      pb.u[0] = pk2(v[mt][0], v[mt][1]);
      pb.u[1] = pk2(v[mt][2], v[mt][3]);
#pragma unroll
      for (int dt = 0; dt < 2; ++dt) {
        // A = pkV[dt][mt] (m=d, k=key tok) -- direct, no va build
        B4 va4;
        va4.u[0] = pkV[dt][mt][0];
        va4.u[1] = pkV[dt][mt][1];
        oacc[dt] = __builtin_amdgcn_mfma_f32_16x16x16bf16_1k(va4.v, pb.v, oacc[dt], 0, 0, 0);
      }
    }

    // deferred normalization: O = inv * (P_raw . V); D-layout identical to v11
    const int to = nt * 16 + j16;
    const int sw = (to & 7) << 5;
#pragma unroll
    for (int dt = 0; dt < 2; ++dt) {
      const int ch0 = wv * 32 + dt * 16 + g * 4;
      const uint2 w2 = make_uint2(pk2(oacc[dt][0] * inv, oacc[dt][1] * inv),
                                  pk2(oacc[dt][2] * inv, oacc[dt][3] * inv));
      *(uint2*)(Ob + to * 256 + ((ch0 * 2) ^ sw)) = w2;
    }
  }
  __syncthreads();

  // ---------------- Phase 4: out = O @ wp^T + b (identical to v11) ----------------
  {
    const char* Ob2 = smem + XO_BASE;
    bf16x8 oa[4][4];
#pragma unroll
    for (int mt = 0; mt < 4; ++mt) {
      const int t = mt * 16 + j16;
      const int sw = (t & 7) << 5;
#pragma unroll
      for (int kt = 0; kt < 4; ++kt)
        oa[mt][kt] = *(const bf16x8*)(Ob2 + t * 256 + ((kt * 64 + g * 16) ^ sw));
    }
    float* ob = out + (size_t)bw * (T49 * CDIM);
#pragma unroll
    for (int ntl = 0; ntl < 2; ++ntl) {
      const int c = (wv * 2 + ntl) * 16 + j16;
      bf16x8 bfr[4];
#pragma unroll
      for (int kt = 0; kt < 4; ++kt)
        bfr[kt] = *(const bf16x8*)(wp + c * CDIM + kt * 32 + g * 8);
      const float bias = b_proj[c];
#pragma unroll
      for (int mt = 0; mt < 4; ++mt) {
        f32x4 acc = {0.f, 0.f, 0.f, 0.f};
#pragma unroll
        for (int kt = 0; kt < 4; ++kt)
          acc = __builtin_amdgcn_mfma_f32_16x16x32_bf16(oa[mt][kt], bfr[kt], acc, 0, 0, 0);
#pragma unroll
        for (int r = 0; r < 4; ++r) {
          const int t = mt * 16 + g * 4 + r;
          if (t < T49) ob[t * CDIM + c] = acc[r] + bias;
        }
      }
    }
  }
}

extern "C" void kernel_launch(void* const* d_in, const int* in_sizes, int n_in,
                              void* d_out, int out_size, void* d_ws, size_t ws_size,
                              hipStream_t stream) {
  const float* x      = (const float*)d_in[0];
  const float* mask   = (const float*)d_in[1];
  const float* w_qkv  = (const float*)d_in[2];
  const float* b_qkv  = (const float*)d_in[3];
  const float* w_proj = (const float*)d_in[4];
  const float* b_proj = (const float*)d_in[5];
  float* out = (float*)d_out;

  float* maskp = (float*)d_ws;                       // 64*64*64 f32 = 1 MB
  short* wq_bf = (short*)((char*)d_ws + 64*64*64*4); // 96 KB
  short* wp_bf = wq_bf + 3 * CDIM * CDIM;            // 32 KB

  hipLaunchKernelGGL(prep_kernel, dim3(1024), dim3(256), 0, stream,
                     w_qkv, w_proj, mask, wq_bf, wp_bf, maskp);
  hipLaunchKernelGGL(winattn_kernel, dim3(8192), dim3(256), 0, stream,
                     x, maskp, b_qkv, b_proj, wq_bf, wp_bf, out);
}